// Round 12
// baseline (366.002 us; speedup 1.0000x reference)
//
#include <hip/hip_runtime.h>

#define N_NODES 100000
#define N_EDGES 3200000
#define NBUCKET 391                  // coarse bucket = dst>>8 (256 nodes each)
#define EPB 8192                     // edges per k_pass1 block
#define NPB ((N_EDGES + EPB - 1) / EPB)  // 391 blocks
#define BCAP 11264                   // per-bucket cap incl self+pad(8)+guard

// ---------------- pass 1: register-resident coarse partition (R9 form) ----------
// item: bits[16:0] = src, bits[24:17] = dst & 255 (bucket = dst>>8).
// Single LDS-atomic round: per-item position packed into bits[31:25].

__global__ void __launch_bounds__(256) k_pass1(const int* __restrict__ src,
                                               const int* __restrict__ dst,
                                               int* __restrict__ gcur,
                                               unsigned int* __restrict__ eb) {
  __shared__ int hist[NBUCKET];
  __shared__ int gbase[NBUCKET];
  int tid = threadIdx.x;
  int base = blockIdx.x * EPB;
  int cnt = min(EPB, N_EDGES - base);   // multiple of 4
  int n4 = cnt >> 2;
  for (int i = tid; i < NBUCKET; i += 256) hist[i] = 0;
  __syncthreads();
  const int4* d4 = (const int4*)(dst + base);
  const int4* s4 = (const int4*)(src + base);
  unsigned mv[32];
  unsigned short mb[32];
#pragma unroll
  for (int k = 0; k < 8; ++k) {
    int i = tid + (k << 8);
    if (i < n4) {
      int4 dv = d4[i];
      int4 sv = s4[i];
      int b0 = dv.x >> 8, b1_ = dv.y >> 8, b2 = dv.z >> 8, b3 = dv.w >> 8;
      unsigned p0 = atomicAdd(&hist[b0], 1);
      unsigned p1 = atomicAdd(&hist[b1_], 1);
      unsigned p2 = atomicAdd(&hist[b2], 1);
      unsigned p3 = atomicAdd(&hist[b3], 1);
      mv[4 * k + 0] = (unsigned)sv.x | ((unsigned)(dv.x & 255) << 17) | (p0 << 25);
      mv[4 * k + 1] = (unsigned)sv.y | ((unsigned)(dv.y & 255) << 17) | (p1 << 25);
      mv[4 * k + 2] = (unsigned)sv.z | ((unsigned)(dv.z & 255) << 17) | (p2 << 25);
      mv[4 * k + 3] = (unsigned)sv.w | ((unsigned)(dv.w & 255) << 17) | (p3 << 25);
      mb[4 * k + 0] = (unsigned short)b0;
      mb[4 * k + 1] = (unsigned short)b1_;
      mb[4 * k + 2] = (unsigned short)b2;
      mb[4 * k + 3] = (unsigned short)b3;
    } else {
      mb[4 * k + 0] = 0xFFFF; mb[4 * k + 1] = 0xFFFF;
      mb[4 * k + 2] = 0xFFFF; mb[4 * k + 3] = 0xFFFF;
    }
  }
  __syncthreads();
  for (int b = tid; b < NBUCKET; b += 256) {
    int h = hist[b];
    gbase[b] = h ? atomicAdd(&gcur[b], h) : 0;   // one claim per (block,bucket)
  }
  __syncthreads();
#pragma unroll
  for (int k = 0; k < 32; ++k) {
    if (mb[k] != 0xFFFF) {
      int b = mb[k];
      unsigned v = mv[k];
      unsigned pos = (unsigned)gbase[b] + (v >> 25);
      if (pos < BCAP) eb[(size_t)b * BCAP + pos] = v & 0x01FFFFFFu;
    }
  }
}

// ---------------- pass 2: counting sort + self-edge + pad-to-8 (R9 form) --------
// Bucket b owns nodes [b*256, b*256+256). Node n's run: [rs[n], re[n]) real
// (self first), pads == N_NODES to a multiple of 8, 16-entry guard after the
// bucket total. Emits dis, xd = x4*dis (+ zero row xd[N_NODES]).

__global__ void __launch_bounds__(256) k_part2(unsigned int* __restrict__ eb,
                                               const int* __restrict__ gcur,
                                               int* __restrict__ rs, int* __restrict__ re,
                                               float* __restrict__ dis,
                                               const float4* __restrict__ x4,
                                               float4* __restrict__ xd) {
  __shared__ int hist[256], scn[256], cur[256];
  __shared__ int tot;
  __shared__ unsigned int stage[BCAP];
  int b = blockIdx.x, tid = threadIdx.x;
  int n0 = b << 8;
  int cnt = min(gcur[b], BCAP);
  int base = b * BCAP;
  hist[tid] = 0; cur[tid] = 0;
  __syncthreads();
  for (int i = tid; i < cnt; i += 256)
    atomicAdd(&hist[eb[base + i] >> 17], 1);
  __syncthreads();
  int n = n0 + tid;
  int deg = hist[tid];
  int slots = (n < N_NODES) ? ((deg + 1 + 7) & ~7) : 0;
  int x = slots;
  scn[tid] = x;
  __syncthreads();
  for (int off = 1; off < 256; off <<= 1) {
    int t = (tid >= off) ? scn[tid - off] : 0;
    __syncthreads();
    x += t; scn[tid] = x;
    __syncthreads();
  }
  int excl = x - slots;
  if (tid == 255) tot = x;
  if (n < N_NODES) {
    rs[n]  = base + excl;
    re[n]  = base + excl + deg + 1;
    float dn = rsqrtf((float)(deg + 1));
    dis[n] = dn;
    float4 xv = x4[n];
    float4 w; w.x = xv.x * dn; w.y = xv.y * dn; w.z = xv.z * dn; w.w = xv.w * dn;
    xd[n] = w;
    stage[excl] = (unsigned)n;                    // self edge
    for (int i = deg + 1; i < slots; ++i)
      stage[excl + i] = (unsigned)N_NODES;        // zero-row pads
  }
  if (b == 0 && tid == 0) xd[N_NODES] = make_float4(0.f, 0.f, 0.f, 0.f);
  scn[tid] = excl + 1;                            // in-edge start
  __syncthreads();
  for (int i = tid; i < cnt; i += 256) {
    unsigned v = eb[base + i];
    unsigned low = v >> 17;
    int lpos = scn[low] + atomicAdd(&cur[low], 1);
    stage[lpos] = v & 0x1FFFFu;
  }
  __syncthreads();
  int total = tot;
  for (int i = tid; i < total; i += 256)
    eb[base + i] = stage[i];     // eb is now padded CSR (src ids by dst node)
  if (tid < 16) {                // guard pads (over-read safety)
    int gp = total + tid;
    if (gp < BCAP) eb[base + gp] = (unsigned)N_NODES;
  }
}

// ---------------- Layer-1 aggregate only: qd[n] = {agg1[n] (4f), dis[n], pad} ---
// 4 threads per node (p = gt&3); stride-4 walk of the padded run (pads hit
// xd's zero row); shfl_xor combine; 32 B struct write.

__global__ void __launch_bounds__(256) k_l1(const float4* __restrict__ xd,
                                            const float* __restrict__ dis,
                                            const int* __restrict__ rs,
                                            const int* __restrict__ re,
                                            const int* __restrict__ csr,
                                            float4* __restrict__ qd) {
  int gt = blockIdx.x * 256 + threadIdx.x;
  int nid = gt >> 2, p = gt & 3;
  if (nid > N_NODES) return;
  if (nid == N_NODES) {                       // zero struct (pad target)
    if (p < 2) qd[(size_t)nid * 2 + p] = make_float4(0.f, 0.f, 0.f, 0.f);
    return;
  }
  int e0 = rs[nid];
  int it4 = ((re[nid] - e0 + 7) & ~7) >> 2;   // dword quads per thread-pass
  const int* cp = csr + e0 + p;
  float ax = 0.f, ay = 0.f, az = 0.f, aw = 0.f;
#pragma unroll 4
  for (int t = 0; t < it4; ++t) {
    int s = cp[t << 2];
    float4 v = xd[s];
    ax += v.x; ay += v.y; az += v.z; aw += v.w;
  }
  ax += __shfl_xor(ax, 1); ax += __shfl_xor(ax, 2);
  ay += __shfl_xor(ay, 1); ay += __shfl_xor(ay, 2);
  az += __shfl_xor(az, 1); az += __shfl_xor(az, 2);
  aw += __shfl_xor(aw, 1); aw += __shfl_xor(aw, 2);
  float dn = dis[nid];
  if (p == 0) qd[(size_t)nid * 2]     = make_float4(ax * dn, ay * dn, az * dn, aw * dn);
  if (p == 1) qd[(size_t)nid * 2 + 1] = make_float4(dn, 0.f, 0.f, 0.f);
}

// ---------------- Layer 2: recompute-h1 broadcast gather + MLP + head -----------
// Wave per node; lane l = output feature j. Per edge s: load qd[s] (32 B,
// L2-resident 3.2 MB table), recompute h1[s][l] = relu((b1[l]+q·W1[:,l])·d)
// (valid since d>0), accumulate. No cross-lane reduction needed.

__global__ void __launch_bounds__(256)
k_layer2(const float4* __restrict__ qd, const float* __restrict__ dis,
         const int* __restrict__ rs, const int* __restrict__ re,
         const int* __restrict__ csr,
         const float* __restrict__ W1, const float* __restrict__ b1,
         const float* __restrict__ W2, const float* __restrict__ b2,
         const float* __restrict__ Wf, const float* __restrict__ bf,
         float* __restrict__ out) {
  __shared__ float sh[4][64];
  int l = threadIdx.x & 63;
  int w = threadIdx.x >> 6;
  int n = blockIdx.x * 4 + w;   // grid = N/4 exactly

  float w0 = W1[l], w1 = W1[64 + l], w2 = W1[128 + l], w3 = W1[192 + l];
  float bj = b1[l];

  int e = rs[n], e1 = re[n];
  float acc0 = 0.f, acc1 = 0.f;
  for (; e + 1 < e1; e += 2) {
    int s0 = csr[e], s1 = csr[e + 1];
    float4 q0 = qd[(size_t)s0 * 2];
    float4 d0 = qd[(size_t)s0 * 2 + 1];
    float4 q1 = qd[(size_t)s1 * 2];
    float4 d1 = qd[(size_t)s1 * 2 + 1];
    float h0 = bj + q0.x * w0 + q0.y * w1 + q0.z * w2 + q0.w * w3;
    float h1 = bj + q1.x * w0 + q1.y * w1 + q1.z * w2 + q1.w * w3;
    acc0 += fmaxf(h0 * d0.x, 0.f);   // relu(x)*d == relu(x*d), d>0
    acc1 += fmaxf(h1 * d1.x, 0.f);
  }
  if (e < e1) {
    int s = csr[e];
    float4 q = qd[(size_t)s * 2];
    float4 d = qd[(size_t)s * 2 + 1];
    float h = bj + q.x * w0 + q.y * w1 + q.z * w2 + q.w * w3;
    acc0 += fmaxf(h * d.x, 0.f);
  }
  sh[w][l] = (acc0 + acc1) * dis[n];   // agg2[n][l] — every lane owns feature l
  __syncthreads();

  float t = b2[l];
  const float4* shv = (const float4*)sh[w];
#pragma unroll 4
  for (int j4 = 0; j4 < 16; ++j4) {
    float4 a4v = shv[j4];
    t += a4v.x * W2[(4 * j4 + 0) * 64 + l];
    t += a4v.y * W2[(4 * j4 + 1) * 64 + l];
    t += a4v.z * W2[(4 * j4 + 2) * 64 + l];
    t += a4v.w * W2[(4 * j4 + 3) * 64 + l];
  }
  t = fmaxf(t, 0.0f);

  float p0 = t * Wf[l * 2 + 0];
  float p1 = t * Wf[l * 2 + 1];
  for (int off = 32; off; off >>= 1) {
    p0 += __shfl_down(p0, off);
    p1 += __shfl_down(p1, off);
  }
  if (l == 0) {
    out[n * 2 + 0] = p0 + bf[0];
    out[n * 2 + 1] = p1 + bf[1];
  }
}

// ---------------- launch ----------------

extern "C" void kernel_launch(void* const* d_in, const int* in_sizes, int n_in,
                              void* d_out, int out_size, void* d_ws, size_t ws_size,
                              hipStream_t stream) {
  const float* x  = (const float*)d_in[0];
  const int*   ei = (const int*)d_in[1];     // [2, E] row-major, int32
  const float* W1 = (const float*)d_in[2];
  const float* b1 = (const float*)d_in[3];
  const float* W2 = (const float*)d_in[4];
  const float* b2 = (const float*)d_in[5];
  const float* Wf = (const float*)d_in[6];
  const float* bf = (const float*)d_in[7];
  float* out = (float*)d_out;

  const int* srcv = ei;
  const int* dstv = ei + N_EDGES;

  char* p = (char*)d_ws;
  auto take = [&](size_t bytes) { char* r = p; p += (bytes + 255) & ~(size_t)255; return r; };
  int*          gcur = (int*)take((size_t)NBUCKET * 4);
  unsigned int* eb   = (unsigned int*)take((size_t)NBUCKET * BCAP * 4 + 512);  // padded CSR
  int*          rs   = (int*)take((size_t)N_NODES * 4);
  int*          re   = (int*)take((size_t)N_NODES * 4);
  float*        dis  = (float*)take((size_t)N_NODES * 4);
  float4*       xd   = (float4*)take((size_t)(N_NODES + 1) * 16);   // + zero row
  float4*       qd   = (float4*)take((size_t)(N_NODES + 1) * 32);   // {agg1, dis} structs

  (void)hipMemsetAsync(gcur, 0, (size_t)NBUCKET * 4, stream);
  k_pass1<<<NPB, 256, 0, stream>>>(srcv, dstv, gcur, eb);
  k_part2<<<NBUCKET, 256, 0, stream>>>(eb, gcur, rs, re, dis, (const float4*)x, xd);
  const int* csr = (const int*)eb;
  k_l1<<<((N_NODES + 1) * 4 + 255) / 256, 256, 0, stream>>>(xd, dis, rs, re, csr, qd);
  k_layer2<<<N_NODES / 4, 256, 0, stream>>>(qd, dis, rs, re, csr, W1, b1, W2, b2, Wf, bf, out);
}

// Round 13
// 270.372 us; speedup vs baseline: 1.3537x; 1.3537x over previous
//
#include <hip/hip_runtime.h>

#define N_NODES 100000
#define N_EDGES 3200000
#define NBUCKET 391                  // coarse bucket = dst>>8 (256 nodes each)
#define EPB 8192                     // edges per k_pass1 block
#define NPB ((N_EDGES + EPB - 1) / EPB)  // 391 blocks
#define BCAP 11264                   // per-bucket cap incl self+pad(8)+guard

// ---------------- pass 1: register-resident coarse partition (R9 form) ----------

__global__ void __launch_bounds__(256) k_pass1(const int* __restrict__ src,
                                               const int* __restrict__ dst,
                                               int* __restrict__ gcur,
                                               unsigned int* __restrict__ eb) {
  __shared__ int hist[NBUCKET];
  __shared__ int gbase[NBUCKET];
  int tid = threadIdx.x;
  int base = blockIdx.x * EPB;
  int cnt = min(EPB, N_EDGES - base);   // multiple of 4
  int n4 = cnt >> 2;
  for (int i = tid; i < NBUCKET; i += 256) hist[i] = 0;
  __syncthreads();
  const int4* d4 = (const int4*)(dst + base);
  const int4* s4 = (const int4*)(src + base);
  unsigned mv[32];
  unsigned short mb[32];
#pragma unroll
  for (int k = 0; k < 8; ++k) {
    int i = tid + (k << 8);
    if (i < n4) {
      int4 dv = d4[i];
      int4 sv = s4[i];
      int b0 = dv.x >> 8, b1_ = dv.y >> 8, b2 = dv.z >> 8, b3 = dv.w >> 8;
      unsigned p0 = atomicAdd(&hist[b0], 1);
      unsigned p1 = atomicAdd(&hist[b1_], 1);
      unsigned p2 = atomicAdd(&hist[b2], 1);
      unsigned p3 = atomicAdd(&hist[b3], 1);
      mv[4 * k + 0] = (unsigned)sv.x | ((unsigned)(dv.x & 255) << 17) | (p0 << 25);
      mv[4 * k + 1] = (unsigned)sv.y | ((unsigned)(dv.y & 255) << 17) | (p1 << 25);
      mv[4 * k + 2] = (unsigned)sv.z | ((unsigned)(dv.z & 255) << 17) | (p2 << 25);
      mv[4 * k + 3] = (unsigned)sv.w | ((unsigned)(dv.w & 255) << 17) | (p3 << 25);
      mb[4 * k + 0] = (unsigned short)b0;
      mb[4 * k + 1] = (unsigned short)b1_;
      mb[4 * k + 2] = (unsigned short)b2;
      mb[4 * k + 3] = (unsigned short)b3;
    } else {
      mb[4 * k + 0] = 0xFFFF; mb[4 * k + 1] = 0xFFFF;
      mb[4 * k + 2] = 0xFFFF; mb[4 * k + 3] = 0xFFFF;
    }
  }
  __syncthreads();
  for (int b = tid; b < NBUCKET; b += 256) {
    int h = hist[b];
    gbase[b] = h ? atomicAdd(&gcur[b], h) : 0;   // one claim per (block,bucket)
  }
  __syncthreads();
#pragma unroll
  for (int k = 0; k < 32; ++k) {
    if (mb[k] != 0xFFFF) {
      int b = mb[k];
      unsigned v = mv[k];
      unsigned pos = (unsigned)gbase[b] + (v >> 25);
      if (pos < BCAP) eb[(size_t)b * BCAP + pos] = v & 0x01FFFFFFu;
    }
  }
}

// ---------------- pass 2: counting sort + self-edge + pad-to-8 (R9 form) --------

__global__ void __launch_bounds__(256) k_part2(unsigned int* __restrict__ eb,
                                               const int* __restrict__ gcur,
                                               int* __restrict__ rs, int* __restrict__ re,
                                               float* __restrict__ dis,
                                               const float4* __restrict__ x4,
                                               float4* __restrict__ xd) {
  __shared__ int hist[256], scn[256], cur[256];
  __shared__ int tot;
  __shared__ unsigned int stage[BCAP];
  int b = blockIdx.x, tid = threadIdx.x;
  int n0 = b << 8;
  int cnt = min(gcur[b], BCAP);
  int base = b * BCAP;
  hist[tid] = 0; cur[tid] = 0;
  __syncthreads();
  for (int i = tid; i < cnt; i += 256)
    atomicAdd(&hist[eb[base + i] >> 17], 1);
  __syncthreads();
  int n = n0 + tid;
  int deg = hist[tid];
  int slots = (n < N_NODES) ? ((deg + 1 + 7) & ~7) : 0;
  int x = slots;
  scn[tid] = x;
  __syncthreads();
  for (int off = 1; off < 256; off <<= 1) {
    int t = (tid >= off) ? scn[tid - off] : 0;
    __syncthreads();
    x += t; scn[tid] = x;
    __syncthreads();
  }
  int excl = x - slots;
  if (tid == 255) tot = x;
  if (n < N_NODES) {
    rs[n]  = base + excl;
    re[n]  = base + excl + deg + 1;
    float dn = rsqrtf((float)(deg + 1));
    dis[n] = dn;
    float4 xv = x4[n];
    float4 w; w.x = xv.x * dn; w.y = xv.y * dn; w.z = xv.z * dn; w.w = xv.w * dn;
    xd[n] = w;
    stage[excl] = (unsigned)n;                    // self edge
    for (int i = deg + 1; i < slots; ++i)
      stage[excl + i] = (unsigned)N_NODES;        // zero-row pads
  }
  if (b == 0 && tid == 0) xd[N_NODES] = make_float4(0.f, 0.f, 0.f, 0.f);
  scn[tid] = excl + 1;                            // in-edge start
  __syncthreads();
  for (int i = tid; i < cnt; i += 256) {
    unsigned v = eb[base + i];
    unsigned low = v >> 17;
    int lpos = scn[low] + atomicAdd(&cur[low], 1);
    stage[lpos] = v & 0x1FFFFu;
  }
  __syncthreads();
  int total = tot;
  for (int i = tid; i < total; i += 256)
    eb[base + i] = stage[i];     // eb is now padded CSR (src ids by dst node)
  if (tid < 16) {                // guard pads (over-read safety)
    int gp = total + tid;
    if (gp < BCAP) eb[base + gp] = (unsigned)N_NODES;
  }
}

// ---------------- Layer-1 aggregate: pd[n] = {agg1[n]*dis[n] (4f), dis[n], 0,0,0}
// 4 threads per node (p = gt&3); stride-4 walk of the padded run (pads hit
// xd's zero row); shfl_xor combine; 32 B struct. Zero struct at N_NODES.

__global__ void __launch_bounds__(256) k_l1(const float4* __restrict__ xd,
                                            const float* __restrict__ dis,
                                            const int* __restrict__ rs,
                                            const int* __restrict__ re,
                                            const int* __restrict__ csr,
                                            float4* __restrict__ pd) {
  int gt = blockIdx.x * 256 + threadIdx.x;
  int nid = gt >> 2, p = gt & 3;
  if (nid > N_NODES) return;
  if (nid == N_NODES) {                       // zero struct (pad target)
    if (p < 2) pd[(size_t)nid * 2 + p] = make_float4(0.f, 0.f, 0.f, 0.f);
    return;
  }
  int e0 = rs[nid];
  int it4 = ((re[nid] - e0 + 7) & ~7) >> 2;   // dword quads per thread-pass
  const int* cp = csr + e0 + p;
  float ax = 0.f, ay = 0.f, az = 0.f, aw = 0.f;
#pragma unroll 4
  for (int t = 0; t < it4; ++t) {
    int s = cp[t << 2];
    float4 v = xd[s];
    ax += v.x; ay += v.y; az += v.z; aw += v.w;
  }
  ax += __shfl_xor(ax, 1); ax += __shfl_xor(ax, 2);
  ay += __shfl_xor(ay, 1); ay += __shfl_xor(ay, 2);
  az += __shfl_xor(az, 1); az += __shfl_xor(az, 2);
  aw += __shfl_xor(aw, 1); aw += __shfl_xor(aw, 2);
  float dn = dis[nid];
  float dn2 = dn * dn;
  if (p == 0) pd[(size_t)nid * 2]     = make_float4(ax * dn2, ay * dn2, az * dn2, aw * dn2);
  if (p == 1) pd[(size_t)nid * 2 + 1] = make_float4(dn, 0.f, 0.f, 0.f);
}

// ---------------- Layer 2: 8-edge-parallel recompute gather + MLP + head --------
// Wave per node. Lane l: g = l>>3 (edge subgroup), c = l&7 (features 8c..8c+7).
// Per 8-edge iteration: 1 csr load + 2 pd loads + 56 VALU. h1s[s][j] =
// relu(p0..3 · W1col_j + p4 · b1[j]); pads (zero struct) contribute 0.
// csr prefetched 2 blocks ahead, pd 1 ahead (guard-safe, addresses only).

__global__ void __launch_bounds__(256)
k_layer2(const float4* __restrict__ pd, const float* __restrict__ dis,
         const int* __restrict__ rs, const int* __restrict__ re,
         const int* __restrict__ csr,
         const float* __restrict__ W1, const float* __restrict__ b1,
         const float* __restrict__ W2, const float* __restrict__ b2,
         const float* __restrict__ Wf, const float* __restrict__ bf,
         float* __restrict__ out) {
  __shared__ float sh[4][64];
  int l = threadIdx.x & 63;
  int w = threadIdx.x >> 6;
  int n = blockIdx.x * 4 + w;   // grid = N/4 exactly
  int g = l >> 3;
  int c = l & 7;
  int j0 = c << 3;

  // this lane's 8 W1-augmented columns (b1 folded via p4 scaling)
  float wA[8], wB[8], wC[8], wD[8], bA[8];
  *(float4*)&wA[0] = *(const float4*)&W1[j0];
  *(float4*)&wA[4] = *(const float4*)&W1[j0 + 4];
  *(float4*)&wB[0] = *(const float4*)&W1[64 + j0];
  *(float4*)&wB[4] = *(const float4*)&W1[64 + j0 + 4];
  *(float4*)&wC[0] = *(const float4*)&W1[128 + j0];
  *(float4*)&wC[4] = *(const float4*)&W1[128 + j0 + 4];
  *(float4*)&wD[0] = *(const float4*)&W1[192 + j0];
  *(float4*)&wD[4] = *(const float4*)&W1[192 + j0 + 4];
  *(float4*)&bA[0] = *(const float4*)&b1[j0];
  *(float4*)&bA[4] = *(const float4*)&b1[j0 + 4];

  const float* pdf = (const float*)pd;
  int e0 = rs[n];
  int iter = (re[n] - e0 + 7) >> 3;           // padded 8-blocks, >= 1
  const int* cb = csr + e0 + g;

  float acc[8] = {0.f, 0.f, 0.f, 0.f, 0.f, 0.f, 0.f, 0.f};
  int sc = cb[0];
  int sn = cb[8];                             // guard-safe
  float4 q = pd[(size_t)sc * 2];
  float  d = pdf[(size_t)sc * 8 + 4];
#define EDGE8(qv, dv)                                                          \
  {                                                                            \
    _Pragma("unroll")                                                          \
    for (int k = 0; k < 8; ++k) {                                              \
      float t = fmaf(qv.x, wA[k], fmaf(qv.y, wB[k],                            \
                fmaf(qv.z, wC[k], fmaf(qv.w, wD[k], dv * bA[k]))));            \
      acc[k] += fmaxf(t, 0.f);                                                 \
    }                                                                          \
  }
  for (int it = 1; it < iter; ++it) {
    int sf = cb[(it + 1) << 3];               // 2-ahead csr (guard-safe)
    float4 qn = pd[(size_t)sn * 2];
    float  dn_ = pdf[(size_t)sn * 8 + 4];
    EDGE8(q, d);
    q = qn; d = dn_; sn = sf;
  }
  EDGE8(q, d);
#undef EDGE8

  // reduce across the 8 edge-subgroups (lane bits 3,4,5)
#pragma unroll
  for (int k = 0; k < 8; ++k) {
    acc[k] += __shfl_xor(acc[k], 8);
    acc[k] += __shfl_xor(acc[k], 16);
    acc[k] += __shfl_xor(acc[k], 32);
  }

  float dnn = dis[n];
  if (l < 8) {                                // l == c: features 8l..8l+7
    float4 v0; v0.x = acc[0] * dnn; v0.y = acc[1] * dnn; v0.z = acc[2] * dnn; v0.w = acc[3] * dnn;
    float4 v1; v1.x = acc[4] * dnn; v1.y = acc[5] * dnn; v1.z = acc[6] * dnn; v1.w = acc[7] * dnn;
    *(float4*)&sh[w][(l << 3) + 0] = v0;
    *(float4*)&sh[w][(l << 3) + 4] = v1;
  }
  __syncthreads();

  float t = b2[l];
  const float4* shv = (const float4*)sh[w];
#pragma unroll 4
  for (int j4 = 0; j4 < 16; ++j4) {
    float4 a4v = shv[j4];
    t += a4v.x * W2[(4 * j4 + 0) * 64 + l];
    t += a4v.y * W2[(4 * j4 + 1) * 64 + l];
    t += a4v.z * W2[(4 * j4 + 2) * 64 + l];
    t += a4v.w * W2[(4 * j4 + 3) * 64 + l];
  }
  t = fmaxf(t, 0.0f);

  float p0 = t * Wf[l * 2 + 0];
  float p1 = t * Wf[l * 2 + 1];
  for (int off = 32; off; off >>= 1) {
    p0 += __shfl_down(p0, off);
    p1 += __shfl_down(p1, off);
  }
  if (l == 0) {
    out[n * 2 + 0] = p0 + bf[0];
    out[n * 2 + 1] = p1 + bf[1];
  }
}

// ---------------- launch ----------------

extern "C" void kernel_launch(void* const* d_in, const int* in_sizes, int n_in,
                              void* d_out, int out_size, void* d_ws, size_t ws_size,
                              hipStream_t stream) {
  const float* x  = (const float*)d_in[0];
  const int*   ei = (const int*)d_in[1];     // [2, E] row-major, int32
  const float* W1 = (const float*)d_in[2];
  const float* b1 = (const float*)d_in[3];
  const float* W2 = (const float*)d_in[4];
  const float* b2 = (const float*)d_in[5];
  const float* Wf = (const float*)d_in[6];
  const float* bf = (const float*)d_in[7];
  float* out = (float*)d_out;

  const int* srcv = ei;
  const int* dstv = ei + N_EDGES;

  char* p = (char*)d_ws;
  auto take = [&](size_t bytes) { char* r = p; p += (bytes + 255) & ~(size_t)255; return r; };
  int*          gcur = (int*)take((size_t)NBUCKET * 4);
  unsigned int* eb   = (unsigned int*)take((size_t)NBUCKET * BCAP * 4 + 512);  // padded CSR
  int*          rs   = (int*)take((size_t)N_NODES * 4);
  int*          re   = (int*)take((size_t)N_NODES * 4);
  float*        dis  = (float*)take((size_t)N_NODES * 4);
  float4*       xd   = (float4*)take((size_t)(N_NODES + 1) * 16);   // + zero row
  float4*       pd   = (float4*)take((size_t)(N_NODES + 1) * 32);   // {agg1*dis, dis} structs

  (void)hipMemsetAsync(gcur, 0, (size_t)NBUCKET * 4, stream);
  k_pass1<<<NPB, 256, 0, stream>>>(srcv, dstv, gcur, eb);
  k_part2<<<NBUCKET, 256, 0, stream>>>(eb, gcur, rs, re, dis, (const float4*)x, xd);
  const int* csr = (const int*)eb;
  k_l1<<<((N_NODES + 1) * 4 + 255) / 256, 256, 0, stream>>>(xd, dis, rs, re, csr, pd);
  k_layer2<<<N_NODES / 4, 256, 0, stream>>>(pd, dis, rs, re, csr, W1, b1, W2, b2, Wf, bf, out);
}